// Round 21
// baseline (571.480 us; speedup 1.0000x reference)
//
#include <hip/hip_runtime.h>
#include <hip/hip_bf16.h>
#include <hip/hip_fp8.h>
#include <math.h>

#define M_TOT 4096
#define K_TOT 1024
#define V_TOT 32000

typedef int int4v __attribute__((ext_vector_type(4)));
typedef int int8v __attribute__((ext_vector_type(8)));
typedef float f32x4 __attribute__((ext_vector_type(4)));

__device__ __forceinline__ void gload_lds16(const void* g, void* l) {
  __builtin_amdgcn_global_load_lds(
      (const __attribute__((address_space(1))) void*)g,
      (__attribute__((address_space(3))) void*)l, 16, 0, 0);
}

__device__ __forceinline__ float sani(float v) {
  return (v != v) ? 0.0f : fminf(fmaxf(v, -1e4f), 1e4f);
}

__device__ __forceinline__ int pk4_fp8(float a, float b, float c, float d) {
#if __has_builtin(__builtin_amdgcn_cvt_pk_fp8_f32)
  int p = __builtin_amdgcn_cvt_pk_fp8_f32(a, b, 0, false);
  p = __builtin_amdgcn_cvt_pk_fp8_f32(c, d, p, true);
  return p;
#else
  union { unsigned char b4[4]; int i; } u;
  u.b4[0] = __hip_fp8_e4m3(a).__x;
  u.b4[1] = __hip_fp8_e4m3(b).__x;
  u.b4[2] = __hip_fp8_e4m3(c).__x;
  u.b4[3] = __hip_fp8_e4m3(d).__x;
  return u.i;
#endif
}

// merged prep: blocks [0,4096) do hidden_states, [4096,36096) do weights.
__global__ void prep_hw(const float* __restrict__ h, const float* __restrict__ w,
                        unsigned char* __restrict__ h8, unsigned char* __restrict__ w8,
                        float* __restrict__ h0, float* __restrict__ wtime) {
  __shared__ float red[4];
  __shared__ float r_sh;
  const int b = blockIdx.x;
  const int t = threadIdx.x;
  if (b < M_TOT) {
    const int m = b;
    const float* row = h + (long)m * (K_TOT + 1);
    if (t == 0) h0[m] = sani(row[0]);
    float4 x = *(const float4*)(row + 1 + t * 4);
    ((int*)(h8 + (long)m * K_TOT))[t] =
        pk4_fp8(sani(x.x), sani(x.y), sani(x.z), sani(x.w));
  } else {
    const int v = b - M_TOT;
    const float* row = w + (long)v * K_TOT;
    float4 x = *(const float4*)(row + t * 4);
    float s = x.x * x.x + x.y * x.y + x.z * x.z + x.w * x.w;
#pragma unroll
    for (int off = 32; off > 0; off >>= 1) s += __shfl_down(s, off);
    int lane = t & 63, wv = t >> 6;
    if (lane == 0) red[wv] = s;
    __syncthreads();
    if (t == 0) {
      float tot = red[0] + red[1] + red[2] + red[3];
      float norm = sqrtf(tot);
      float r = (norm > 1e-7f) ? (sinhf(norm) / fmaxf(norm, 1e-7f)) : 1.0f;
      r_sh = r;
      wtime[v] = coshf(norm);
    }
    __syncthreads();
    float sc = 16.0f * r_sh;  // 16x prescale; undone by MFMA scaleA = 2^-4
    ((int*)(w8 + (long)v * K_TOT))[t] =
        pk4_fp8(sc * x.x, sc * x.y, sc * x.z, sc * x.w);
  }
}

// == 128x256 tile, BK=128 MX-fp8, r18 layout/ledger, 8 waves x 64x64/wave ==
// The 2->4 waves/SIMD experiment. Every r11-r20 variant had acc=128 AGPR +
// ~110 VGPR -> 2 waves/SIMD, so each vmcnt/BAR/LDS bubble has <=1 alt wave:
// the measured serial pipe-sum. Here per-wave state halves: 8 waves (2Mx4N),
// per-wave 64x64 output -> acc[4][4] = 64 AGPR; bv[4] 32 VGPR + streamed av
// + addr ~= 110-125 combined <= 128 cap (launch_bounds(512,4)) -> 4
// waves/SIMD, 2 blocks/CU (LDS 64KB x2 = 128 <= 160).
// NOTE r4 distinction: r4's disaster was acc(128) > cap(64) -> ACC spill.
// Here acc(64) fits comfortably; only addressing temps are at risk.
// Layout/ledger = r18 verbatim, scaled to 512 threads (6 stage-loads/iter):
//   A dbuf 2x16KB @0 (row*128+c*16), B single 32KB @32768.
//   iter kt: bv[4]+av[4] LDS reads; LGKM0+schedbar+BAR (seals reads);
//   STAGE_B(kt+1)[4 ops] + STAGE_A(kt+2 -> just-read A buf)[2 ops];
//   16 MFMA (av streamed inside im-loop, setprio-wrapped);
//   VM2 (proves A(kt+1)[2]+B(kt+1)[4]; A(kt+2)'s 2 stay in flight); BAR.
// Prologue: A(0)[2]+B(0)[4]+A(1)[2]; VM2 proves A0+B0.
// Zero-conflict swizzle (r11-r20): slot chunk c = global c^(row&7); source
// pre-swizzled cc=(t&7)^((t>>3)&7); read chunks (2fq+h)^(fr&7).
// r17 grid map (FETCH 42MB), r16 batched nt stores (full 128B lines).
#define BAR __builtin_amdgcn_s_barrier()
#define LGKM0 asm volatile("s_waitcnt lgkmcnt(0)" ::: "memory")
#define VM2 asm volatile("s_waitcnt vmcnt(2)" ::: "memory")

__global__ __launch_bounds__(512, 4) void gemm_geo(
    const unsigned char* __restrict__ h8, const unsigned char* __restrict__ w8,
    const float* __restrict__ h0, const float* __restrict__ wtime,
    const float* __restrict__ ls, float* __restrict__ out) {
  __shared__ __align__(16) char smem[65536];  // A: 2x16KB | B: 32KB @32768

  const int t = threadIdx.x;
  const int wave = t >> 6, lane = t & 63;
  const int fr = lane & 15, fq = lane >> 4;
  const int wm = wave >> 2, wn = wave & 3;  // 2 (M) x 4 (N) wave grid

  // r17 grid map (FETCH=42MB): per-XCD contiguous chunks; 16-block groups
  // share (B-panel 256KB, A-half 2MB); m-half-major across panels.
  const int bid = blockIdx.x;
  const int swz = (bid & 7) * 500 + (bid >> 3);
  const int g = swz >> 4;                  // [0,250)
  const int sub = swz & 15;
  const int half = (g >= 125) ? 1 : 0;
  const int tile_v = g - half * 125;       // [0,125)
  const int tile_m = half * 16 + sub;      // [0,32)
  const int row0 = tile_m * 128;
  const int col0 = tile_v * 256;

  // read-side lane constants (bytes)
  const int xorv = fr & 7;
  const int c0 = ((2 * fq) ^ xorv) * 16;
  const int c1 = ((2 * fq + 1) ^ xorv) * 16;
  const int a_rd = (wm * 64 + fr) * 128;            // + buf*16384 + im*2048
  const int b_rd = 32768 + (wn * 64 + fr) * 128;    // + iv*2048

  auto RDF = [&](int off) -> int8v {
    int4v lo = *(const int4v*)(smem + off + c0);
    int4v hi = *(const int4v*)(smem + off + c1);
    return (int8v){lo[0], lo[1], lo[2], lo[3], hi[0], hi[1], hi[2], hi[3]};
  };

  // staging: 512 threads; thread t -> row hh*64 + (t>>3), slot chunk t&7,
  // source pre-swizzled (rule #21: gload_lds writes linearly; row&7 =
  // (t>>3)&7 since hh*64 doesn't touch bits 0-2)
  const int cc = (t & 7) ^ ((t >> 3) & 7);
  const unsigned char* pA = h8 + ((long)row0 + (t >> 3)) * K_TOT + cc * 16;
  const unsigned char* pB = w8 + ((long)col0 + (t >> 3)) * K_TOT + cc * 16;
  const int dst_w = wave * 1024;  // wave-uniform; HW adds lane*16

  auto STAGE_A = [&](int kt, int bufo) {
#pragma unroll
    for (int hh = 0; hh < 2; ++hh)  // 128 rows = 2 x 64-row batches
      gload_lds16(pA + (long)hh * (64L * K_TOT) + kt * 128,
                  smem + bufo + hh * 8192 + dst_w);
  };
  auto STAGE_B = [&](int kt) {
#pragma unroll
    for (int hh = 0; hh < 4; ++hh)  // 256 rows = 4 x 64-row batches
      gload_lds16(pB + (long)hh * (64L * K_TOT) + kt * 128,
                  smem + 32768 + hh * 8192 + dst_w);
  };

  f32x4 acc[4][4];
#pragma unroll
  for (int i = 0; i < 4; ++i)
#pragma unroll
    for (int j = 0; j < 4; ++j) acc[i][j] = (f32x4)(0.0f);

  // prologue: A(0)->buf0 [2], B(0) [4], A(1)->buf1 [2]; VM2 proves A0+B0.
  STAGE_A(0, 0);
  STAGE_B(0);
  STAGE_A(1, 16384);
  VM2;
  BAR;

#pragma unroll 1
  for (int kt = 0; kt < 8; ++kt) {
    const int cbo = (kt & 1) << 14;
    const int skB = (kt + 1 < 8) ? kt + 1 : 7;  // clamped redundant tail
    const int skA = (kt + 2 < 8) ? kt + 2 : 7;

    int8v bv[4];
#pragma unroll
    for (int iv = 0; iv < 4; ++iv) bv[iv] = RDF(b_rd + iv * 2048);
    int8v av0 = RDF(cbo + a_rd);
    int8v av1 = RDF(cbo + a_rd + 2048);
    int8v av2 = RDF(cbo + a_rd + 4096);
    int8v av3 = RDF(cbo + a_rd + 6144);
    LGKM0;
    __builtin_amdgcn_sched_barrier(0);
    BAR;  // all waves sealed their B + A(kt) reads

    STAGE_B(skB);        // B(kt+1) -> the single B buffer [4 ops]
    STAGE_A(skA, cbo);   // A(kt+2) -> the A buffer just read [2 ops]

    __builtin_amdgcn_s_setprio(1);
#pragma unroll
    for (int iv = 0; iv < 4; ++iv) {
      acc[0][iv] = __builtin_amdgcn_mfma_scale_f32_16x16x128_f8f6f4(
          bv[iv], av0, acc[0][iv], 0, 0, 0, 0x7B7B7B7B, 0, 0x7F7F7F7F);
      acc[1][iv] = __builtin_amdgcn_mfma_scale_f32_16x16x128_f8f6f4(
          bv[iv], av1, acc[1][iv], 0, 0, 0, 0x7B7B7B7B, 0, 0x7F7F7F7F);
      acc[2][iv] = __builtin_amdgcn_mfma_scale_f32_16x16x128_f8f6f4(
          bv[iv], av2, acc[2][iv], 0, 0, 0, 0x7B7B7B7B, 0, 0x7F7F7F7F);
      acc[3][iv] = __builtin_amdgcn_mfma_scale_f32_16x16x128_f8f6f4(
          bv[iv], av3, acc[3][iv], 0, 0, 0, 0x7B7B7B7B, 0, 0x7F7F7F7F);
    }
    __builtin_amdgcn_s_setprio(0);

    // carried A(kt+1)[2] + B(kt+1)[4] + A(kt+2)[2] = 8 outstanding;
    // VM2 proves A(kt+1)+B(kt+1); A(kt+2)'s 2 stay in flight.
    VM2;
    BAR;
  }

  // fused epilogue: x = h0*w_time - dot; d2 = acosh(x)^2; out = -tau*d2.
  // Per row: 4 f32x4 computed, then 4 nt stores back-to-back (full 128B
  // lines, r16's write-combine fix). 4 waves/SIMD hide the drain.
  const float ntau = -fminf(fmaxf(ls[0], 0.01f), 2.5f);
  const float LN2 = 0.69314718055994531f;
  f32x4 wt4[4];
#pragma unroll
  for (int iv = 0; iv < 4; ++iv)
    wt4[iv] = *(const f32x4*)&wtime[col0 + wn * 64 + iv * 16 + fq * 4];
#pragma unroll
  for (int im = 0; im < 4; ++im) {
    const float hh = h0[row0 + wm * 64 + im * 16 + fr];
    float* orow = out + (long)(row0 + wm * 64 + im * 16 + fr) * V_TOT + col0 +
                  wn * 64;
    f32x4 rv[4];
#pragma unroll
    for (int iv = 0; iv < 4; ++iv) {
#pragma unroll
      for (int j = 0; j < 4; ++j) {
        float x = fmaf(hh, wt4[iv][j], -acc[im][iv][j]);
        float xm1 = fmaxf(x - 1.0f, 0.0f);
        float arg = fmaxf(fmaf(x, x, -1.0f), 0.0f);
        float lg2 = __builtin_amdgcn_logf(x + __builtin_amdgcn_sqrtf(arg));
        float dex = LN2 * lg2;
        float d2_exact = dex * dex;
        float ts = fmaf(xm1, -1.0f / 12.0f, 1.0f);
        float d2_tay = 2.0f * xm1 * ts * ts;
        float d2 = (xm1 < 1e-3f) ? d2_tay : d2_exact;
        rv[iv][j] = ntau * d2;
      }
    }
#pragma unroll
    for (int iv = 0; iv < 4; ++iv)
      __builtin_nontemporal_store(rv[iv], (f32x4*)(orow + iv * 16 + fq * 4));
  }
}

extern "C" void kernel_launch(void* const* d_in, const int* in_sizes, int n_in,
                              void* d_out, int out_size, void* d_ws, size_t ws_size,
                              hipStream_t stream) {
  const float* h = (const float*)d_in[0];   // [2,2048,1025]
  const float* w = (const float*)d_in[1];   // [32000,1024]
  const float* ls = (const float*)d_in[2];  // scalar
  float* out = (float*)d_out;               // [2,2048,32000] fp32

  char* ws = (char*)d_ws;
  unsigned char* w8 = (unsigned char*)ws;                     // 32,768,000 B
  unsigned char* h8 = (unsigned char*)(ws + 32768000);        // 4,194,304 B
  float* wtime = (float*)(ws + 32768000 + 4194304);           // 128,000 B
  float* h0 = (float*)(ws + 32768000 + 4194304 + 128000);     // 16,384 B

  prep_hw<<<M_TOT + V_TOT, 256, 0, stream>>>(h, w, h8, w8, h0, wtime);
  gemm_geo<<<4000, 512, 0, stream>>>(h8, w8, h0, wtime, ls, out);
}

// Round 22
// 267.820 us; speedup vs baseline: 2.1338x; 2.1338x over previous
//
#include <hip/hip_runtime.h>
#include <hip/hip_bf16.h>
#include <hip/hip_fp8.h>
#include <math.h>

#define M_TOT 4096
#define K_TOT 1024
#define V_TOT 32000

typedef int int4v __attribute__((ext_vector_type(4)));
typedef int int8v __attribute__((ext_vector_type(8)));
typedef float f32x4 __attribute__((ext_vector_type(4)));

__device__ __forceinline__ void gload_lds16(const void* g, void* l) {
  __builtin_amdgcn_global_load_lds(
      (const __attribute__((address_space(1))) void*)g,
      (__attribute__((address_space(3))) void*)l, 16, 0, 0);
}

__device__ __forceinline__ float sani(float v) {
  return (v != v) ? 0.0f : fminf(fmaxf(v, -1e4f), 1e4f);
}

__device__ __forceinline__ int pk4_fp8(float a, float b, float c, float d) {
#if __has_builtin(__builtin_amdgcn_cvt_pk_fp8_f32)
  int p = __builtin_amdgcn_cvt_pk_fp8_f32(a, b, 0, false);
  p = __builtin_amdgcn_cvt_pk_fp8_f32(c, d, p, true);
  return p;
#else
  union { unsigned char b4[4]; int i; } u;
  u.b4[0] = __hip_fp8_e4m3(a).__x;
  u.b4[1] = __hip_fp8_e4m3(b).__x;
  u.b4[2] = __hip_fp8_e4m3(c).__x;
  u.b4[3] = __hip_fp8_e4m3(d).__x;
  return u.i;
#endif
}

// merged prep: blocks [0,4096) do hidden_states, [4096,36096) do weights.
__global__ void prep_hw(const float* __restrict__ h, const float* __restrict__ w,
                        unsigned char* __restrict__ h8, unsigned char* __restrict__ w8,
                        float* __restrict__ h0, float* __restrict__ wtime) {
  __shared__ float red[4];
  __shared__ float r_sh;
  const int b = blockIdx.x;
  const int t = threadIdx.x;
  if (b < M_TOT) {
    const int m = b;
    const float* row = h + (long)m * (K_TOT + 1);
    if (t == 0) h0[m] = sani(row[0]);
    float4 x = *(const float4*)(row + 1 + t * 4);
    ((int*)(h8 + (long)m * K_TOT))[t] =
        pk4_fp8(sani(x.x), sani(x.y), sani(x.z), sani(x.w));
  } else {
    const int v = b - M_TOT;
    const float* row = w + (long)v * K_TOT;
    float4 x = *(const float4*)(row + t * 4);
    float s = x.x * x.x + x.y * x.y + x.z * x.z + x.w * x.w;
#pragma unroll
    for (int off = 32; off > 0; off >>= 1) s += __shfl_down(s, off);
    int lane = t & 63, wv = t >> 6;
    if (lane == 0) red[wv] = s;
    __syncthreads();
    if (t == 0) {
      float tot = red[0] + red[1] + red[2] + red[3];
      float norm = sqrtf(tot);
      float r = (norm > 1e-7f) ? (sinhf(norm) / fmaxf(norm, 1e-7f)) : 1.0f;
      r_sh = r;
      wtime[v] = coshf(norm);
    }
    __syncthreads();
    float sc = 16.0f * r_sh;  // 16x prescale; undone by MFMA scaleA = 2^-4
    ((int*)(w8 + (long)v * K_TOT))[t] =
        pk4_fp8(sc * x.x, sc * x.y, sc * x.z, sc * x.w);
  }
}

// == 128x256 tile, BK=128 MX-fp8: A-dbuf(2x16K) + B-sgl(32K) = 64KB LDS,
// == 2 blocks/CU. FINAL (r18, measured best 268.1us).
// Design-space bracket (all measured):
//   - 4 waves/SIMD (r21) / (512,4) cap (r4): register spill -> 2-8x HBM
//   - smaller tiles / 2-blocks-via-halving (r13): staging traffic x2 -> loss
//   - B-in-registers (r17): 64 live VGPRs across sync -> latency collapse
//   - store-interleave in K-loop (r12): breaks conflict-free scheduling
//   - deep prefetch (r6), 4-phase (r5), 8-phase-counted (r10), desync (r19),
//     LDS-pipe-cut (r20): all neutral at 2 waves/SIMD
// Won levers baked in: fp8 MX K=128 (r11, -100us), nt stores (r14, -17us),
// batched 128B-line stores (r16), L2-fit grid map (r15/r17: FETCH 355->42MB),
// zero-conflict both-sides XOR swizzle (r4-: conflicts == 0), operand-swap
// epilogue with float4 stores (r7: WRITE = 513MB ideal), merged prep (r15).
// Per-iter ledger (2 BAR, 1 counted VM4):
//   bv[8]+av[4] LDS reads; LGKM0+schedbar+BAR (seals reads);
//   STAGE_B(kt+1) -> single B buf [8]; STAGE_A(kt+2) -> just-read A buf [4];
//   32 MFMA (setprio); VM4 proves A(kt+1)+B(kt+1), A(kt+2) flies; BAR.
#define BAR __builtin_amdgcn_s_barrier()
#define LGKM0 asm volatile("s_waitcnt lgkmcnt(0)" ::: "memory")
#define VM4 asm volatile("s_waitcnt vmcnt(4)" ::: "memory")

__global__ __launch_bounds__(256, 2) void gemm_geo(
    const unsigned char* __restrict__ h8, const unsigned char* __restrict__ w8,
    const float* __restrict__ h0, const float* __restrict__ wtime,
    const float* __restrict__ ls, float* __restrict__ out) {
  __shared__ __align__(16) char smem[65536];  // A: 2x16KB | B: 32KB @32768

  const int t = threadIdx.x;
  const int wave = t >> 6, lane = t & 63;
  const int fr = lane & 15, fq = lane >> 4;
  const int wm = wave >> 1, wn = wave & 1;  // 2 (M) x 2 (N) wave grid

  // r17 grid map (FETCH=42MB): per-XCD contiguous chunks; 16-block groups
  // share (B-panel 256KB, A-half 2MB); m-half-major across panels.
  const int bid = blockIdx.x;
  const int swz = (bid & 7) * 500 + (bid >> 3);
  const int g = swz >> 4;                  // [0,250)
  const int sub = swz & 15;
  const int half = (g >= 125) ? 1 : 0;
  const int tile_v = g - half * 125;       // [0,125)
  const int tile_m = half * 16 + sub;      // [0,32)
  const int row0 = tile_m * 128;
  const int col0 = tile_v * 256;

  // read-side lane constants (bytes)
  const int xorv = fr & 7;
  const int c0 = ((2 * fq) ^ xorv) * 16;
  const int c1 = ((2 * fq + 1) ^ xorv) * 16;
  const int a_rd = (wm * 64 + fr) * 128;            // + buf*16384 + im*2048
  const int b_rd = 32768 + (wn * 128 + fr) * 128;   // + iv*2048

  auto RDF = [&](int off) -> int8v {
    int4v lo = *(const int4v*)(smem + off + c0);
    int4v hi = *(const int4v*)(smem + off + c1);
    return (int8v){lo[0], lo[1], lo[2], lo[3], hi[0], hi[1], hi[2], hi[3]};
  };

  // staging: thread t -> row (t>>3) within 32-row batch, slot chunk t&7,
  // source pre-swizzled (rule #21: gload_lds writes linearly)
  const int cc = (t & 7) ^ ((t >> 3) & 7);
  const unsigned char* pA = h8 + ((long)row0 + (t >> 3)) * K_TOT + cc * 16;
  const unsigned char* pB = w8 + ((long)col0 + (t >> 3)) * K_TOT + cc * 16;
  const int dst_w = wave * 1024;  // wave-uniform; HW adds lane*16

  auto STAGE_A = [&](int kt, int bufo) {
#pragma unroll
    for (int hh = 0; hh < 4; ++hh)
      gload_lds16(pA + (long)hh * (32L * K_TOT) + kt * 128,
                  smem + bufo + hh * 4096 + dst_w);
  };
  auto STAGE_B = [&](int kt) {
#pragma unroll
    for (int hh = 0; hh < 8; ++hh)
      gload_lds16(pB + (long)hh * (32L * K_TOT) + kt * 128,
                  smem + 32768 + hh * 4096 + dst_w);
  };

  f32x4 acc[4][8];
#pragma unroll
  for (int i = 0; i < 4; ++i)
#pragma unroll
    for (int j = 0; j < 8; ++j) acc[i][j] = (f32x4)(0.0f);

  // prologue: A(0)->buf0 [4], B(0) [8], A(1)->buf1 [4]; VM4 proves A0+B0.
  STAGE_A(0, 0);
  STAGE_B(0);
  STAGE_A(1, 16384);
  VM4;
  BAR;

#pragma unroll 1
  for (int kt = 0; kt < 8; ++kt) {
    const int cbo = (kt & 1) << 14;
    const int skB = (kt + 1 < 8) ? kt + 1 : 7;  // clamped redundant tail
    const int skA = (kt + 2 < 8) ? kt + 2 : 7;

    int8v bv[8], av[4];
#pragma unroll
    for (int iv = 0; iv < 8; ++iv) bv[iv] = RDF(b_rd + iv * 2048);
#pragma unroll
    for (int im = 0; im < 4; ++im) av[im] = RDF(cbo + a_rd + im * 2048);
    LGKM0;
    __builtin_amdgcn_sched_barrier(0);
    BAR;  // all waves sealed their B + A(kt) reads

    STAGE_B(skB);        // B(kt+1) -> the single B buffer
    STAGE_A(skA, cbo);   // A(kt+2) -> the A buffer just read

    __builtin_amdgcn_s_setprio(1);
#pragma unroll
    for (int im = 0; im < 4; ++im)
#pragma unroll
      for (int iv = 0; iv < 8; ++iv)
        acc[im][iv] = __builtin_amdgcn_mfma_scale_f32_16x16x128_f8f6f4(
            bv[iv], av[im], acc[im][iv], 0, 0, 0, 0x7B7B7B7B, 0, 0x7F7F7F7F);
    __builtin_amdgcn_s_setprio(0);

    // carried A(kt+1)[4] + B(kt+1)[8] + A(kt+2)[4] = 16 outstanding;
    // VM4 proves A(kt+1)+B(kt+1); A(kt+2)'s 4 stay in flight.
    VM4;
    BAR;
  }

  // fused epilogue: x = h0*w_time - dot; d2 = acosh(x)^2; out = -tau*d2.
  // Per row: 8 f32x4 computed, then 8 nt stores back-to-back (full 128B
  // lines, r16's write-combine fix). Co-resident block hides the drain.
  const float ntau = -fminf(fmaxf(ls[0], 0.01f), 2.5f);
  const float LN2 = 0.69314718055994531f;
  f32x4 wt4[8];
#pragma unroll
  for (int iv = 0; iv < 8; ++iv)
    wt4[iv] = *(const f32x4*)&wtime[col0 + wn * 128 + iv * 16 + fq * 4];
#pragma unroll
  for (int im = 0; im < 4; ++im) {
    const float hh = h0[row0 + wm * 64 + im * 16 + fr];
    float* orow = out + (long)(row0 + wm * 64 + im * 16 + fr) * V_TOT + col0 +
                  wn * 128;
    f32x4 rv[8];
#pragma unroll
    for (int iv = 0; iv < 8; ++iv) {
#pragma unroll
      for (int j = 0; j < 4; ++j) {
        float x = fmaf(hh, wt4[iv][j], -acc[im][iv][j]);
        float xm1 = fmaxf(x - 1.0f, 0.0f);
        float arg = fmaxf(fmaf(x, x, -1.0f), 0.0f);
        float lg2 = __builtin_amdgcn_logf(x + __builtin_amdgcn_sqrtf(arg));
        float dex = LN2 * lg2;
        float d2_exact = dex * dex;
        float ts = fmaf(xm1, -1.0f / 12.0f, 1.0f);
        float d2_tay = 2.0f * xm1 * ts * ts;
        float d2 = (xm1 < 1e-3f) ? d2_tay : d2_exact;
        rv[iv][j] = ntau * d2;
      }
    }
#pragma unroll
    for (int iv = 0; iv < 8; ++iv)
      __builtin_nontemporal_store(rv[iv], (f32x4*)(orow + iv * 16 + fq * 4));
  }
}

extern "C" void kernel_launch(void* const* d_in, const int* in_sizes, int n_in,
                              void* d_out, int out_size, void* d_ws, size_t ws_size,
                              hipStream_t stream) {
  const float* h = (const float*)d_in[0];   // [2,2048,1025]
  const float* w = (const float*)d_in[1];   // [32000,1024]
  const float* ls = (const float*)d_in[2];  // scalar
  float* out = (float*)d_out;               // [2,2048,32000] fp32

  char* ws = (char*)d_ws;
  unsigned char* w8 = (unsigned char*)ws;                     // 32,768,000 B
  unsigned char* h8 = (unsigned char*)(ws + 32768000);        // 4,194,304 B
  float* wtime = (float*)(ws + 32768000 + 4194304);           // 128,000 B
  float* h0 = (float*)(ws + 32768000 + 4194304 + 128000);     // 16,384 B

  prep_hw<<<M_TOT + V_TOT, 256, 0, stream>>>(h, w, h8, w8, h0, wtime);
  gemm_geo<<<4000, 256, 0, stream>>>(h8, w8, h0, wtime, ls, out);
}